// Round 6
// baseline (216.030 us; speedup 1.0000x reference)
//
#include <hip/hip_runtime.h>
#include <float.h>
#include <math.h>

#define BATCH 8
#define CHN   128
#define NPTS  2048
#define KNN   9
#define NOUT  256
#define TOTCNT (BATCH*NPTS*KNN)

typedef __attribute__((ext_vector_type(8))) short short8;
typedef __attribute__((ext_vector_type(4))) float f32x4;

__device__ __forceinline__ unsigned short f2bf(float f) {
    unsigned int u = __float_as_uint(f);
    unsigned int r = (u + 0x7FFFu + ((u >> 16) & 1u)) >> 16;
    return (unsigned short)r;
}
__device__ __forceinline__ float bf2f(unsigned short h) {
    return __uint_as_float(((unsigned int)h) << 16);
}

// ---------------- kernel 1: transpose + bf16 split + 0.5*sqnorm (+ W split + stats zero) ----------------
__global__ __launch_bounds__(256) void prep_kernel(const float* __restrict__ x,
                                                   const float* __restrict__ W,
                                                   unsigned short* __restrict__ xhi,
                                                   unsigned short* __restrict__ xlo,
                                                   unsigned short* __restrict__ whi,
                                                   unsigned short* __restrict__ wlo,
                                                   float* __restrict__ sqh,
                                                   float* __restrict__ stats) {
    __shared__ float xt[128 * 65];
    __shared__ float psq[256];
    const int b = blockIdx.x, tid = threadIdx.x;
    if (blockIdx.y == 32) {   // W -> Bcat=[W1-W2; W2] hi/lo split + zero this batch's stats copy
        stats[b * 512 + tid] = 0.f;
        stats[b * 512 + 256 + tid] = 0.f;
#pragma unroll
        for (int e = 0; e < 32; ++e) {
            int idx = e * 256 + tid;
            int r = b * 64 + (idx >> 7), c = idx & 127;
            float v = (r < 256) ? (W[r * 256 + c] - W[r * 256 + 128 + c])
                                : W[(r - 256) * 256 + 128 + c];
            unsigned short h = f2bf(v);
            float hf = bf2f(h);
            whi[r * 128 + c] = h;
            wlo[r * 128 + c] = f2bf(v - hf);
        }
        return;
    }
    const int n0 = blockIdx.y * 64;
#pragma unroll 4
    for (int p = 0; p < 32; ++p) {
        int c = p * 4 + (tid >> 6), n = tid & 63;
        xt[c * 65 + n] = x[((size_t)b * CHN + c) * NPTS + n0 + n];
    }
    __syncthreads();
    const int n = tid >> 2, cq = tid & 3;
    size_t row = (size_t)(b * NPTS + n0 + n) * CHN;
    float s = 0.f;
#pragma unroll 8
    for (int j = 0; j < 32; ++j) {
        int c = cq * 32 + j;
        float f = xt[c * 65 + n];
        unsigned short h = f2bf(f);
        float hf = bf2f(h);
        unsigned short l = f2bf(f - hf);
        xhi[row + c] = h;
        xlo[row + c] = l;
        s += f * f;
    }
    psq[tid] = s;
    __syncthreads();
    if (tid < 64)
        sqh[b * NPTS + n0 + tid] =
            0.5f * (psq[tid*4] + psq[tid*4+1] + psq[tid*4+2] + psq[tid*4+3]);
}

// ---------------- kernel 2: knn + pq, 512-THREAD blocks + MIN-EXTRACT scan (R6) -------------------------
// R5 post-mortem arithmetic: 8.1K VALU insts/wave; the always-taken (any-of-64-lanes) gated 4x 29-op
// insertion chains were the invariant bottleneck across R0-R5; occupancy 23% exposed the dep-chains.
// R6a: 8-wave blocks -- all waves share one staged chunk stream (LDS still 32 KB, staging traffic
//      halved, 2x waves per resident block). knn: 128 queries/block. pq: two old tiles per block.
// R6b: min-extract scan -- 21-op min-idx tree reduces 8 candidates to one insert (29-op chain) per
//      round + mask/retree retry for rare multi-insert chunks; cross-quad shared threshold (quads
//      hold disjoint m of the SAME query; min of their dl[8]s is a provably safe gate: the union
//      already has 9 elements <= it) tightens gates at the 512-stream rate.
__global__ __launch_bounds__(512) void knnpq_mfma(const unsigned short* __restrict__ xhi,
                                                  const unsigned short* __restrict__ xlo,
                                                  const float* __restrict__ sqh,
                                                  const unsigned short* __restrict__ whi,
                                                  const unsigned short* __restrict__ wlo,
                                                  float* __restrict__ pd,
                                                  int* __restrict__ pi,
                                                  float* __restrict__ p,
                                                  unsigned short* __restrict__ q) {
    // [buf][plane][32 rows][16 slots of 16B]: 2*2*32*256 B = 32 KB
    __shared__ __align__(16) unsigned short aS[16384];

    const int tid = threadIdx.x;
    const int b  = blockIdx.x;          // batch fastest -> XCD k serves batch k (L2 affinity)
    const int zr = blockIdx.z;
    const int sub = zr >> 1;            // 0..3 within role
    const int wv = tid >> 6, lane = tid & 63;
    const int quad = lane >> 4, col = lane & 15;
    const int koff = quad * 8;
    const size_t xb = (size_t)b * NPTS * CHN;

    if (zr & 1) {
        // ------------- pq path: two 256n x 32o tiles per block (wave halves), acc[4][2]/wave -----------
        const int nt = blockIdx.y >> 1;                               // 0..7
        const int ot = ((blockIdx.y & 1) << 3) | (sub << 1) | (wv >> 2);  // 0..15
        const int w4 = wv & 3;
        const int nbase = nt * 256 + w4 * 64;
        const int obase = ot * 32;                                    // row in Bcat [512]

        f32x4 acc[4][2];
#pragma unroll
        for (int i = 0; i < 4; ++i)
#pragma unroll
            for (int j = 0; j < 2; ++j) acc[i][j] = (f32x4)0.f;

        for (int chk = 0; chk < 4; ++chk) {
            short8 ah[4], al[4];
#pragma unroll
            for (int i = 0; i < 4; ++i) {
                size_t g = xb + (size_t)(nbase + i * 16 + col) * CHN + chk * 32 + koff;
                ah[i] = *(const short8*)&xhi[g];
                al[i] = *(const short8*)&xlo[g];
            }
#pragma unroll
            for (int j = 0; j < 2; ++j) {
                size_t g = (size_t)(obase + j * 16 + col) * CHN + chk * 32 + koff;
                short8 bh = *(const short8*)&whi[g];
                short8 bl = *(const short8*)&wlo[g];
#pragma unroll
                for (int i = 0; i < 4; ++i) {
                    acc[i][j] = __builtin_amdgcn_mfma_f32_16x16x32_bf16(ah[i], bh, acc[i][j], 0, 0, 0);
                    acc[i][j] = __builtin_amdgcn_mfma_f32_16x16x32_bf16(ah[i], bl, acc[i][j], 0, 0, 0);
                    acc[i][j] = __builtin_amdgcn_mfma_f32_16x16x32_bf16(al[i], bh, acc[i][j], 0, 0, 0);
                }
            }
        }
#pragma unroll
        for (int i = 0; i < 4; ++i)
#pragma unroll
            for (int j = 0; j < 2; ++j) {
                int oc = (obase + j * 16 + col) & 255;
#pragma unroll
                for (int r = 0; r < 4; ++r) {
                    int n = nbase + i * 16 + quad * 4 + r;
                    size_t off = (size_t)(b * NPTS + n) * NOUT + oc;
                    if (ot < 8) p[off] = acc[i][j][r];
                    else        q[off] = f2bf(acc[i][j][r]);
                }
            }
        return;
    }

    // ---------------- knn path: 128 queries (8 waves x 16), 512-row m slice ----------------
    const int q0 = blockIdx.y * 128, ms = sub;
    const int msbase = ms * 512;
    const int myq = q0 + wv * 16 + col;           // this lane's query (D col = lane&15)

    // query B-frags, both planes, resident in 32 VGPRs
    short8 qh[4], ql[4];
    {
        const unsigned short* qrh = xhi + xb + (size_t)myq * CHN + koff;
        const unsigned short* qrl = xlo + xb + (size_t)myq * CHN + koff;
#pragma unroll
        for (int chk = 0; chk < 4; ++chk) {
            qh[chk] = *(const short8*)(qrh + chk * 32);
            ql[chk] = *(const short8*)(qrl + chk * 32);
        }
    }

    float dl[KNN]; int il[KNN];
#pragma unroll
    for (int k = 0; k < KNN; ++k) { dl[k] = FLT_MAX; il[k] = 0; }
    float thr = FLT_MAX;                 // shared (cross-quad) gate threshold, <= dl[8]

    // ungated sorted insert (caller guarantees v < dl[KNN-1]); strict < keeps earlier idx on tie
    auto ins_nochk = [&](float v, int idx) {
        bool c0b = v < dl[0];
#pragma unroll
        for (int k = KNN - 1; k >= 1; --k) {
            bool sh   = v < dl[k - 1];
            bool here = v < dl[k];
            float nd = sh ? dl[k - 1] : (here ? v : dl[k]);
            int   ni = sh ? il[k - 1] : (here ? idx : il[k]);
            dl[k] = nd; il[k] = ni;
        }
        if (c0b) { dl[0] = v; il[0] = idx; }
    };
    // merge insert: tie-aware (smaller m-idx wins on equal value)
    auto ins2 = [&](float v, int idx) {
        if ((v < dl[KNN - 1]) || (v == dl[KNN - 1] && idx < il[KNN - 1])) {
            bool c0b = (v < dl[0]) || (v == dl[0] && idx < il[0]);
#pragma unroll
            for (int k = KNN - 1; k >= 1; --k) {
                bool sh   = (v < dl[k - 1]) || (v == dl[k - 1] && idx < il[k - 1]);
                bool here = (v < dl[k])     || (v == dl[k]     && idx < il[k]);
                float nd = sh ? dl[k - 1] : (here ? v : dl[k]);
                int   ni = sh ? il[k - 1] : (here ? idx : il[k]);
                dl[k] = nd; il[k] = ni;
            }
            if (c0b) { dl[0] = v; il[0] = idx; }
        }
    };

    // ---- staging (512 thr): plane t in {0,1}; row = tid>>4 (0..31); dest slot linear (tid*16 B);
    //      source col = (tid&15) ^ (row&15)  [both-sides involution; read xor cancels at row=col] ----
    const unsigned short* gsrc[2];
    {
        const int rA = tid >> 4;                       // 0..31
        const int sc8 = ((tid & 15) ^ (rA & 15)) << 3; // swizzled source col * 8 elements
        gsrc[0] = xhi + xb + (size_t)(msbase + rA) * CHN + sc8;
        gsrc[1] = xlo + xb + (size_t)(msbase + rA) * CHN + sc8;
    }
    short8 stv[2];
    auto stage_load = [&](int ch) {
        stv[0] = *(const short8*)(gsrc[0] + (size_t)ch * (32 * CHN));
        stv[1] = *(const short8*)(gsrc[1] + (size_t)ch * (32 * CHN));
    };
    auto stage_write = [&](int bf) {
        char* d = (char*)aS + bf * 16384 + tid * 16;
        *(short8*)(d)        = stv[0];
        *(short8*)(d + 8192) = stv[1];
    };

    // frag-read constants: byte = buf*16384 + plane*8192 + (half*16+col)*256 + ((chk*4+quad)^col)*16
    const int rowb = col << 8;
    int cofs[4];
#pragma unroll
    for (int chk = 0; chk < 4; ++chk)
        cofs[chk] = (((chk << 2) | quad) ^ col) << 4;
    const float* smb = sqh + b * NPTS + msbase + quad * 4;

    // prologue: ch0 staged, ch1 in regs
    stage_load(0);
    stage_write(0);
    stage_load(1);
    __syncthreads();

    int buf = 0;
    for (int ch = 0; ch < 16; ++ch) {
        if (ch < 15) stage_write(buf ^ 1);     // regs hold ch+1
        if (ch < 14) stage_load(ch + 2);       // prefetch ch+2 into regs

        const char* ab = (const char*)aS + buf * 16384;
        float4 s0 = *(const float4*)(smb + ch * 32);
        float4 s1 = *(const float4*)(smb + ch * 32 + 16);

        f32x4 acc[2];
        acc[0] = (f32x4)0.f; acc[1] = (f32x4)0.f;
#pragma unroll
        for (int chk = 0; chk < 4; ++chk) {
            short8 mh0 = *(const short8*)(ab + rowb + cofs[chk]);
            short8 mh1 = *(const short8*)(ab + 4096 + rowb + cofs[chk]);
            short8 ml0 = *(const short8*)(ab + 8192 + rowb + cofs[chk]);
            short8 ml1 = *(const short8*)(ab + 12288 + rowb + cofs[chk]);
            acc[0] = __builtin_amdgcn_mfma_f32_16x16x32_bf16(mh0, qh[chk], acc[0], 0, 0, 0);
            acc[0] = __builtin_amdgcn_mfma_f32_16x16x32_bf16(mh0, ql[chk], acc[0], 0, 0, 0);
            acc[0] = __builtin_amdgcn_mfma_f32_16x16x32_bf16(ml0, qh[chk], acc[0], 0, 0, 0);
            acc[1] = __builtin_amdgcn_mfma_f32_16x16x32_bf16(mh1, qh[chk], acc[1], 0, 0, 0);
            acc[1] = __builtin_amdgcn_mfma_f32_16x16x32_bf16(mh1, ql[chk], acc[1], 0, 0, 0);
            acc[1] = __builtin_amdgcn_mfma_f32_16x16x32_bf16(ml1, qh[chk], acc[1], 0, 0, 0);
        }

        // ---- min-extract scan: m = msbase + ch*32 + {0,16} + quad*4 + r; rel idx {0..3, 16..19} ----
        const int ib = msbase + (ch << 5) + (quad << 2);
        float d0 = s0.x - acc[0][0], d1 = s0.y - acc[0][1];
        float d2 = s0.z - acc[0][2], d3 = s0.w - acc[0][3];
        float d4 = s1.x - acc[1][0], d5 = s1.y - acc[1][1];
        float d6 = s1.z - acc[1][2], d7 = s1.w - acc[1][3];

        for (;;) {
            // min-idx tree (ordered args -> ties resolve to smaller idx)
            float m01 = fminf(d0, d1); int i01 = (d1 < d0) ? 1  : 0;
            float m23 = fminf(d2, d3); int i23 = (d3 < d2) ? 3  : 2;
            float m45 = fminf(d4, d5); int i45 = (d5 < d4) ? 17 : 16;
            float m67 = fminf(d6, d7); int i67 = (d7 < d6) ? 19 : 18;
            float mA  = fminf(m01, m23); int iA = (m23 < m01) ? i23 : i01;
            float mB  = fminf(m45, m67); int iB = (m67 < m45) ? i67 : i45;
            float mv  = fminf(mA, mB);   int mi = (mB < mA)   ? iB  : iA;
            bool pass = mv < thr;
            if (!__any(pass)) break;
            if (pass) ins_nochk(mv, ib + mi);
            thr = fminf(thr, dl[KNN - 1]);
            // mask extracted min everywhere (non-passing lanes' mins are >= thr: provably useless)
            d0 = (mi == 0)  ? FLT_MAX : d0;
            d1 = (mi == 1)  ? FLT_MAX : d1;
            d2 = (mi == 2)  ? FLT_MAX : d2;
            d3 = (mi == 3)  ? FLT_MAX : d3;
            d4 = (mi == 16) ? FLT_MAX : d4;
            d5 = (mi == 17) ? FLT_MAX : d5;
            d6 = (mi == 18) ? FLT_MAX : d6;
            d7 = (mi == 19) ? FLT_MAX : d7;
        }

        // cross-quad threshold share (same query across quads; min of dl[8]s is a safe global gate)
        {
            float t = fminf(dl[KNN - 1], __shfl_xor(dl[KNN - 1], 16, 64));
            t = fminf(t, __shfl_xor(t, 32, 64));
            thr = fminf(thr, t);
        }

        __syncthreads();
        buf ^= 1;
    }

    // cross-quad merge: quads partition m mod 16; 2 butterfly rounds leave full top-9 in every lane
#pragma unroll
    for (int rd = 0; rd < 2; ++rd) {
        const int xm = 16 << rd;
        float pv[KNN]; int pix[KNN];
#pragma unroll
        for (int k = 0; k < KNN; ++k) {
            pv[k]  = __shfl_xor(dl[k], xm, 64);
            pix[k] = __shfl_xor(il[k], xm, 64);
        }
#pragma unroll
        for (int k = 0; k < KNN; ++k) ins2(pv[k], pix[k]);
    }

    if (quad == 0) {
        size_t ob = ((size_t)(b * NPTS + myq) * 4 + ms) * KNN;
#pragma unroll
        for (int k = 0; k < KNN; ++k) {
            pd[ob + k] = dl[k];
            pi[ob + k] = il[k];
        }
    }
}

// ---------------- kernel 3: merge FUSED + BN stats + packed bf16 (hmax,hmin); 512 thr (R3) ---------------
__global__ __launch_bounds__(512) void stats2_kernel(const float* __restrict__ p,
                                                     const unsigned short* __restrict__ q,
                                                     const float* __restrict__ pd,
                                                     const int* __restrict__ pi,
                                                     float* __restrict__ stats,
                                                     unsigned int* __restrict__ hmm) {
    __shared__ int idx_s[16 * KNN];
    const int b = blockIdx.x, n0 = blockIdx.y * 16;
    const int tid = threadIdx.x;
    const int o = tid & 255, half = tid >> 8;
    if (tid < 16) {
        size_t g = (size_t)(b * NPTS + n0 + tid) * 36;
        const float* d = pd + g;
        const int*   i = pi + g;
        int p0 = 0, p1 = 0, p2 = 0, p3 = 0;
#pragma unroll
        for (int k = 0; k < KNN; ++k) {
            float v0 = (p0 < KNN) ? d[p0]      : FLT_MAX;
            float v1 = (p1 < KNN) ? d[9 + p1]  : FLT_MAX;
            float v2 = (p2 < KNN) ? d[18 + p2] : FLT_MAX;
            float v3 = (p3 < KNN) ? d[27 + p3] : FLT_MAX;
            float best = v0; int sel = 0;
            if (v1 < best) { best = v1; sel = 1; }
            if (v2 < best) { best = v2; sel = 2; }
            if (v3 < best) { best = v3; sel = 3; }
            int idx;
            if      (sel == 0) { idx = i[p0];      p0++; }
            else if (sel == 1) { idx = i[9 + p1];  p1++; }
            else if (sel == 2) { idx = i[18 + p2]; p2++; }
            else               { idx = i[27 + p3]; p3++; }
            idx_s[tid * KNN + k] = idx;
        }
    }
    __syncthreads();
    const unsigned short* qb = q + (size_t)b * NPTS * NOUT + o;
    float s = 0.f, ss = 0.f;
    const int qbase = half * 8;
    for (int qq = 0; qq < 8; qq += 2) {
        const int qi = qbase + qq;
        size_t off0 = (size_t)(b * NPTS + n0 + qi) * NOUT + o;
        size_t off1 = off0 + NOUT;
        float pv0 = p[off0], pv1 = p[off1];
        float h0[KNN], h1[KNN];
#pragma unroll
        for (int k = 0; k < KNN; ++k)
            h0[k] = bf2f(qb[(size_t)idx_s[qi * KNN + k] * NOUT]);
#pragma unroll
        for (int k = 0; k < KNN; ++k)
            h1[k] = bf2f(qb[(size_t)idx_s[(qi + 1) * KNN + k] * NOUT]);
        float mx0 = -FLT_MAX, mn0 = FLT_MAX, mx1 = -FLT_MAX, mn1 = FLT_MAX;
#pragma unroll
        for (int k = 0; k < KNN; ++k) {
            float a = pv0 + h0[k], c = pv1 + h1[k];
            s += a + c; ss += a * a + c * c;
            mx0 = fmaxf(mx0, a); mn0 = fminf(mn0, a);
            mx1 = fmaxf(mx1, c); mn1 = fminf(mn1, c);
        }
        hmm[off0] = ((unsigned int)f2bf(mx0) << 16) | f2bf(mn0);
        hmm[off1] = ((unsigned int)f2bf(mx1) << 16) | f2bf(mn1);
    }
    atomicAdd(&stats[b * 512 + o], s);
    atomicAdd(&stats[b * 512 + NOUT + o], ss);
}

// ---------------- kernel 4: normalize + relu + max_k, transposed store; 512 thr (R3) ----------------
__global__ __launch_bounds__(512) void final_kernel(const unsigned int* __restrict__ hmm,
                                                    const float* __restrict__ stats,
                                                    const float* __restrict__ gamma,
                                                    const float* __restrict__ beta,
                                                    float* __restrict__ out) {
    __shared__ float tr[256 * 17];
    const int b = blockIdx.x, n0 = blockIdx.y * 16;
    const int tid = threadIdx.x;
    const int o = tid & 255, qh = tid >> 8;
    float sum = 0.f, sumsq = 0.f;
#pragma unroll
    for (int i = 0; i < 8; ++i) {
        sum   += stats[i * 512 + o];
        sumsq += stats[i * 512 + NOUT + o];
    }
    const float inv = 1.f / (float)TOTCNT;
    float mean = sum * inv;
    float var  = sumsq * inv - mean * mean;
    float g    = gamma[o] / sqrtf(var + 1e-5f);
    float bet  = beta[o];
    const bool pos = (g >= 0.f);
#pragma unroll
    for (int qq = 0; qq < 8; ++qq) {
        const int qi = qh * 8 + qq;
        size_t off = (size_t)(b * NPTS + n0 + qi) * NOUT + o;
        unsigned int w = hmm[off];
        float v = bf2f(pos ? (unsigned short)(w >> 16) : (unsigned short)(w & 0xFFFFu));
        float hn = (v - mean) * g + bet;
        tr[o * 17 + qi] = fmaxf(hn, 0.f);
    }
    __syncthreads();
    int oo = tid >> 4, qq = tid & 15;    // oo 0..31
    for (int pass = 0; pass < 8; ++pass) {
        int o_ = pass * 32 + oo;
        out[((size_t)b * NOUT + o_) * NPTS + n0 + qq] = tr[o_ * 17 + qq];
    }
}

extern "C" void kernel_launch(void* const* d_in, const int* in_sizes, int n_in,
                              void* d_out, int out_size, void* d_ws, size_t ws_size,
                              hipStream_t stream) {
    (void)in_sizes; (void)n_in; (void)out_size; (void)ws_size;
    const float* x     = (const float*)d_in[0];
    const float* W     = (const float*)d_in[1];
    const float* gamma = (const float*)d_in[2];
    const float* beta  = (const float*)d_in[3];
    float* out = (float*)d_out;

    char* ws = (char*)d_ws;
    float*          p     = (float*)ws;                                   // 16 MB fp32
    unsigned short* q     = (unsigned short*)(ws + (16u << 20));          // 8 MB bf16
    unsigned short* xhi   = (unsigned short*)(ws + (24u << 20));          // 4 MB
    unsigned short* xlo   = (unsigned short*)(ws + (28u << 20));          // 4 MB
    unsigned int*   hmm   = (unsigned int*)(ws + (32u << 20));            // 16 MB
    unsigned short* whi   = (unsigned short*)(ws + (48u << 20));          // 128 KB
    unsigned short* wlo   = (unsigned short*)(ws + (48u << 20) + 131072); // 128 KB
    float*          pd    = (float*)(ws + (49u << 20));                   // 2.25 MB
    int*            pi    = (int*)  (ws + (52u << 20));                   // 2.25 MB
    float*          sqh   = (float*)(ws + (55u << 20));                   // 64 KB
    float*          stats = (float*)(ws + (55u << 20) + 65536);           // 16 KB

    prep_kernel  <<<dim3(8, 33),    256, 0, stream>>>(x, W, xhi, xlo, whi, wlo, sqh, stats);
    knnpq_mfma   <<<dim3(8, 16, 8), 512, 0, stream>>>(xhi, xlo, sqh, whi, wlo, pd, pi, p, q);
    stats2_kernel<<<dim3(8, 128),   512, 0, stream>>>(p, q, pd, pi, stats, hmm);
    final_kernel <<<dim3(8, 128),   512, 0, stream>>>(hmm, stats, gamma, beta, out);
}

// Round 7
// 200.324 us; speedup vs baseline: 1.0784x; 1.0784x over previous
//
#include <hip/hip_runtime.h>
#include <float.h>
#include <math.h>

#define BATCH 8
#define CHN   128
#define NPTS  2048
#define KNN   9
#define NOUT  256
#define TOTCNT (BATCH*NPTS*KNN)

typedef __attribute__((ext_vector_type(8))) short short8;
typedef __attribute__((ext_vector_type(4))) float f32x4;

__device__ __forceinline__ unsigned short f2bf(float f) {
    unsigned int u = __float_as_uint(f);
    unsigned int r = (u + 0x7FFFu + ((u >> 16) & 1u)) >> 16;
    return (unsigned short)r;
}
__device__ __forceinline__ float bf2f(unsigned short h) {
    return __uint_as_float(((unsigned int)h) << 16);
}

// ---------------- kernel 1: transpose + bf16 split + 0.5*sqnorm (+ W split + stats zero) ----------------
// R7: store phase rewritten for coalescing. Old phase-2 wrote 2B per lane scattered across 64 distinct
// 64B lines per store instr (32x sector write-amplification, 128 store instrs). New: 16-lane group owns
// one point-row; lane converts 8 contiguous channels -> short8 16B stores (one instr = 1KB dense);
// sqnorm via 4-step shfl_xor reduce within the 16-lane group. 32 dense store instrs total.
__global__ __launch_bounds__(256) void prep_kernel(const float* __restrict__ x,
                                                   const float* __restrict__ W,
                                                   unsigned short* __restrict__ xhi,
                                                   unsigned short* __restrict__ xlo,
                                                   unsigned short* __restrict__ whi,
                                                   unsigned short* __restrict__ wlo,
                                                   float* __restrict__ sqh,
                                                   float* __restrict__ stats) {
    __shared__ float xt[128 * 65];
    __shared__ float psq[64];
    const int b = blockIdx.x, tid = threadIdx.x;
    if (blockIdx.y == 32) {   // W -> Bcat=[W1-W2; W2] hi/lo split + zero this batch's stats copy
        stats[b * 512 + tid] = 0.f;
        stats[b * 512 + 256 + tid] = 0.f;
#pragma unroll
        for (int e = 0; e < 32; ++e) {
            int idx = e * 256 + tid;
            int r = b * 64 + (idx >> 7), c = idx & 127;
            float v = (r < 256) ? (W[r * 256 + c] - W[r * 256 + 128 + c])
                                : W[(r - 256) * 256 + 128 + c];
            unsigned short h = f2bf(v);
            float hf = bf2f(h);
            whi[r * 128 + c] = h;
            wlo[r * 128 + c] = f2bf(v - hf);
        }
        return;
    }
    const int n0 = blockIdx.y * 64;
#pragma unroll 4
    for (int p = 0; p < 32; ++p) {
        int c = p * 4 + (tid >> 6), n = tid & 63;
        xt[c * 65 + n] = x[((size_t)b * CHN + c) * NPTS + n0 + n];
    }
    __syncthreads();
    const int lane = tid & 63, wv = tid >> 6;
    const int r16 = lane >> 4;           // 0..3 row within wave-pass
    const int c8  = (lane & 15) * 8;     // 8 contiguous channels per lane
#pragma unroll
    for (int pass = 0; pass < 4; ++pass) {
        const int n = pass * 16 + wv * 4 + r16;     // 0..63, unique per (pass,wv,r16)
        float s = 0.f;
        short8 hv, lv;
#pragma unroll
        for (int j = 0; j < 8; ++j) {
            float f = xt[(c8 + j) * 65 + n];
            unsigned short h = f2bf(f);
            float hf = bf2f(h);
            hv[j] = (short)h;
            lv[j] = (short)f2bf(f - hf);
            s = fmaf(f, f, s);
        }
        size_t row = (size_t)(b * NPTS + n0 + n) * CHN + c8;
        *(short8*)&xhi[row] = hv;
        *(short8*)&xlo[row] = lv;
        // reduce across the 16 lanes sharing this row (lane bits 0..3)
        s += __shfl_xor(s, 1, 64);
        s += __shfl_xor(s, 2, 64);
        s += __shfl_xor(s, 4, 64);
        s += __shfl_xor(s, 8, 64);
        if ((lane & 15) == 0) psq[n] = s;
    }
    __syncthreads();
    if (tid < 64)
        sqh[b * NPTS + n0 + tid] = 0.5f * psq[tid];
}

// ---------------- kernel 2: knn + pq, z-PARITY role interleave (R3 verbatim — best measured 104.0) -----
// Six rounds of restructuring (LDS-transpose / register-direct / LDS-shared / min-extract) all land
// 104-125 us with VALUBusy*dur ~constant; this decomposition's floor is ~104. Frozen at R3.
__global__ __launch_bounds__(256) void knnpq_mfma(const unsigned short* __restrict__ xhi,
                                                  const unsigned short* __restrict__ xlo,
                                                  const float* __restrict__ sqh,
                                                  const unsigned short* __restrict__ whi,
                                                  const unsigned short* __restrict__ wlo,
                                                  float* __restrict__ pd,
                                                  int* __restrict__ pi,
                                                  float* __restrict__ p,
                                                  unsigned short* __restrict__ q) {
    __shared__ __align__(16) unsigned short aS[8192];   // 16 KB: A-hi tile, swizzled rows
    __shared__ __align__(16) float dts[5120];           // 20 KB: 4 wave-private 64x20 dump regions; merge reuses

    const int tid = threadIdx.x;
    const int b  = blockIdx.x;          // batch fastest -> XCD k serves batch k (L2 affinity)
    const int zr = blockIdx.z;
    const int sub = zr >> 1;            // 0..3 within role
    const int wv = tid >> 6, lane = tid & 63;
    const int quad = lane >> 4, col = lane & 15;
    const int koff = quad * 8;
    const size_t xb = (size_t)b * NPTS * CHN;

    if (zr & 1) {
        // ---------------- pq path: 256n x 32o per block, acc[4][2] per wave ----------------
        const int nt = blockIdx.y >> 2;
        const int ot = ((blockIdx.y & 3) << 2) | sub;                 // 0..15
        const int nbase = nt * 256 + wv * 64;
        const int obase = ot * 32;                                    // row in Bcat [512]

        f32x4 acc[4][2];
#pragma unroll
        for (int i = 0; i < 4; ++i)
#pragma unroll
            for (int j = 0; j < 2; ++j) acc[i][j] = (f32x4)0.f;

        for (int chk = 0; chk < 4; ++chk) {
            short8 ah[4], al[4];
#pragma unroll
            for (int i = 0; i < 4; ++i) {
                size_t g = xb + (size_t)(nbase + i * 16 + col) * CHN + chk * 32 + koff;
                ah[i] = *(const short8*)&xhi[g];
                al[i] = *(const short8*)&xlo[g];
            }
#pragma unroll
            for (int j = 0; j < 2; ++j) {
                size_t g = (size_t)(obase + j * 16 + col) * CHN + chk * 32 + koff;
                short8 bh = *(const short8*)&whi[g];
                short8 bl = *(const short8*)&wlo[g];
#pragma unroll
                for (int i = 0; i < 4; ++i) {
                    acc[i][j] = __builtin_amdgcn_mfma_f32_16x16x32_bf16(ah[i], bh, acc[i][j], 0, 0, 0);
                    acc[i][j] = __builtin_amdgcn_mfma_f32_16x16x32_bf16(ah[i], bl, acc[i][j], 0, 0, 0);
                    acc[i][j] = __builtin_amdgcn_mfma_f32_16x16x32_bf16(al[i], bh, acc[i][j], 0, 0, 0);
                }
            }
        }
#pragma unroll
        for (int i = 0; i < 4; ++i)
#pragma unroll
            for (int j = 0; j < 2; ++j) {
                int oc = (obase + j * 16 + col) & 255;
#pragma unroll
                for (int r = 0; r < 4; ++r) {
                    int n = nbase + i * 16 + quad * 4 + r;
                    size_t off = (size_t)(b * NPTS + n) * NOUT + oc;
                    if (ot < 8) p[off] = acc[i][j][r];
                    else        q[off] = f2bf(acc[i][j][r]);
                }
            }
        return;
    }

    // ---------------- knn path ----------------
    const int q0 = blockIdx.y * 64, ms = sub;
    const int msbase = ms * 512;
    const int mcol0 = wv * 32;

    // ---- stage A-hi tile (64q x 256B rows) into LDS, swizzle byte ^= (row&7)<<4 (both sides) ----
#pragma unroll
    for (int t = 0; t < 4; ++t) {
        const int row = t * 16 + (tid >> 4);            // 0..63
        const int off = (tid & 15) << 4;                // 16B-aligned byte col in [0,256)
        short8 v = *(const short8*)&xhi[xb + (size_t)(q0 + row) * CHN + (off >> 1)];
        *(short8*)((char*)aS + row * 256 + (off ^ ((row & 7) << 4))) = v;
    }
    __syncthreads();

    float* dtw = &dts[wv * 1280];        // this wave's private 64q x 20-stride region

    float dl[KNN]; int il[KNN];
#pragma unroll
    for (int k = 0; k < KNN; ++k) { dl[k] = FLT_MAX; il[k] = 0; }

    auto ins = [&](float v, int idx) {
        if (v < dl[KNN - 1]) {
            bool c0b = v < dl[0];
#pragma unroll
            for (int k = KNN - 1; k >= 1; --k) {
                bool sh   = v < dl[k - 1];
                bool here = v < dl[k];
                float nd = sh ? dl[k - 1] : (here ? v : dl[k]);
                int   ni = sh ? il[k - 1] : (here ? idx : il[k]);
                dl[k] = nd; il[k] = ni;
            }
            if (c0b) { dl[0] = v; il[0] = idx; }
        }
    };

    const int sw  = (col & 7) << 4;      // row-derived swizzle (row&7 == col&7 for rows i*16+col)
    const int q16 = quad << 4;
    const int cb  = col << 8;
    const char* ab = (const char*)aS;
    // hoisted A-lo base: per-lane row q0+col, offsets i*16 rows (i*4096 B) + chk*64 B are constants
    const unsigned short* albase = xlo + xb + (size_t)(q0 + col) * CHN + koff;

    for (int iter = 0; iter < 4; ++iter) {
        const int mbase = msbase + iter * 128;
        float sm[2];
#pragma unroll
        for (int j = 0; j < 2; ++j)
            sm[j] = sqh[b * NPTS + mbase + mcol0 + j * 16 + col];

        // one 64-bit base per iter; per-load offsets are compile-time constants
        const size_t boff = xb + (size_t)(mbase + mcol0 + col) * CHN + koff;
        const unsigned short* bph = xhi + boff;
        const unsigned short* bpl = xlo + boff;

        f32x4 acc[4][2];
#pragma unroll
        for (int i = 0; i < 4; ++i)
#pragma unroll
            for (int j = 0; j < 2; ++j) acc[i][j] = (f32x4)0.f;

#pragma unroll
        for (int chk = 0; chk < 4; ++chk) {
            const int o = cb + (((chk << 6) + q16) ^ sw);
            short8 ah[4], al[4];
#pragma unroll
            for (int i = 0; i < 4; ++i) {
                ah[i] = *(const short8*)(ab + i * 4096 + o);
                al[i] = *(const short8*)(albase + i * 2048 + chk * 32);
            }
#pragma unroll
            for (int j = 0; j < 2; ++j) {
                short8 bh = *(const short8*)(bph + j * 2048 + chk * 32);
                short8 bl = *(const short8*)(bpl + j * 2048 + chk * 32);
#pragma unroll
                for (int i = 0; i < 4; ++i) {
                    acc[i][j] = __builtin_amdgcn_mfma_f32_16x16x32_bf16(ah[i], bh, acc[i][j], 0, 0, 0);
                    acc[i][j] = __builtin_amdgcn_mfma_f32_16x16x32_bf16(ah[i], bl, acc[i][j], 0, 0, 0);
                    acc[i][j] = __builtin_amdgcn_mfma_f32_16x16x32_bf16(al[i], bh, acc[i][j], 0, 0, 0);
                }
            }
        }

        // per-j dump 64q x 16m into wave-private region, then scan own row.
        // same-wave DS ordering handles RAW (dump->scan) and WAR (scan j0 -> dump j1).
        const int ibase = mbase + mcol0;
#pragma unroll
        for (int j = 0; j < 2; ++j) {
#pragma unroll
            for (int i = 0; i < 4; ++i)
#pragma unroll
                for (int r = 0; r < 4; ++r) {
                    int q_ = i * 16 + quad * 4 + r;
                    dtw[q_ * 20 + col] = sm[j] - acc[i][j][r];
                }
#pragma unroll
            for (int jj = 0; jj < 4; ++jj) {
                float4 v = *(const float4*)&dtw[lane * 20 + jj * 4];
                float mn4 = fminf(fminf(v.x, v.y), fminf(v.z, v.w));
                if (mn4 < dl[KNN - 1]) {
                    int ib = ibase + j * 16 + jj * 4;
                    ins(v.x, ib); ins(v.y, ib + 1); ins(v.z, ib + 2); ins(v.w, ib + 3);
                }
            }
        }
    }

    // merge: wave w holds query l's top-9 over its 128 cols in lane l
    __syncthreads();                     // all waves done scanning before merge-area writes
    float* md = dts;                     // 64 x 36 floats
    int*   mi = (int*)(dts + 2304);      // 64 x 36 ints
#pragma unroll
    for (int k = 0; k < KNN; ++k) {
        md[lane * 36 + wv * 9 + k] = dl[k];
        mi[lane * 36 + wv * 9 + k] = il[k];
    }
    __syncthreads();
    if (tid < 64) {
        int base = tid * 36;
        int p0 = 0, p1 = 0, p2 = 0, p3 = 0;
        size_t ob = ((size_t)(b * NPTS + q0 + tid) * 4 + ms) * KNN;
        for (int k = 0; k < KNN; ++k) {
            float v0 = (p0 < KNN) ? md[base + p0]      : FLT_MAX;
            float v1 = (p1 < KNN) ? md[base + 9 + p1]  : FLT_MAX;
            float v2 = (p2 < KNN) ? md[base + 18 + p2] : FLT_MAX;
            float v3 = (p3 < KNN) ? md[base + 27 + p3] : FLT_MAX;
            float best = v0; int sel = 0;
            if (v1 < best) { best = v1; sel = 1; }
            if (v2 < best) { best = v2; sel = 2; }
            if (v3 < best) { best = v3; sel = 3; }
            int idx;
            if      (sel == 0) { idx = mi[base + p0];      p0++; }
            else if (sel == 1) { idx = mi[base + 9 + p1];  p1++; }
            else if (sel == 2) { idx = mi[base + 18 + p2]; p2++; }
            else               { idx = mi[base + 27 + p3]; p3++; }
            pd[ob + k] = best;
            pi[ob + k] = idx;
        }
    }
}

// ---------------- kernel 3: merge FUSED + BN stats + packed bf16 (hmax,hmin); 512 thr ---------------
__global__ __launch_bounds__(512) void stats2_kernel(const float* __restrict__ p,
                                                     const unsigned short* __restrict__ q,
                                                     const float* __restrict__ pd,
                                                     const int* __restrict__ pi,
                                                     float* __restrict__ stats,
                                                     unsigned int* __restrict__ hmm) {
    __shared__ int idx_s[16 * KNN];
    const int b = blockIdx.x, n0 = blockIdx.y * 16;
    const int tid = threadIdx.x;
    const int o = tid & 255, half = tid >> 8;
    if (tid < 16) {
        size_t g = (size_t)(b * NPTS + n0 + tid) * 36;
        const float* d = pd + g;
        const int*   i = pi + g;
        int p0 = 0, p1 = 0, p2 = 0, p3 = 0;
#pragma unroll
        for (int k = 0; k < KNN; ++k) {
            float v0 = (p0 < KNN) ? d[p0]      : FLT_MAX;
            float v1 = (p1 < KNN) ? d[9 + p1]  : FLT_MAX;
            float v2 = (p2 < KNN) ? d[18 + p2] : FLT_MAX;
            float v3 = (p3 < KNN) ? d[27 + p3] : FLT_MAX;
            float best = v0; int sel = 0;
            if (v1 < best) { best = v1; sel = 1; }
            if (v2 < best) { best = v2; sel = 2; }
            if (v3 < best) { best = v3; sel = 3; }
            int idx;
            if      (sel == 0) { idx = i[p0];      p0++; }
            else if (sel == 1) { idx = i[9 + p1];  p1++; }
            else if (sel == 2) { idx = i[18 + p2]; p2++; }
            else               { idx = i[27 + p3]; p3++; }
            idx_s[tid * KNN + k] = idx;
        }
    }
    __syncthreads();
    const unsigned short* qb = q + (size_t)b * NPTS * NOUT + o;
    float s = 0.f, ss = 0.f;
    const int qbase = half * 8;
    for (int qq = 0; qq < 8; qq += 2) {
        const int qi = qbase + qq;
        size_t off0 = (size_t)(b * NPTS + n0 + qi) * NOUT + o;
        size_t off1 = off0 + NOUT;
        float pv0 = p[off0], pv1 = p[off1];
        float h0[KNN], h1[KNN];
#pragma unroll
        for (int k = 0; k < KNN; ++k)
            h0[k] = bf2f(qb[(size_t)idx_s[qi * KNN + k] * NOUT]);
#pragma unroll
        for (int k = 0; k < KNN; ++k)
            h1[k] = bf2f(qb[(size_t)idx_s[(qi + 1) * KNN + k] * NOUT]);
        float mx0 = -FLT_MAX, mn0 = FLT_MAX, mx1 = -FLT_MAX, mn1 = FLT_MAX;
#pragma unroll
        for (int k = 0; k < KNN; ++k) {
            float a = pv0 + h0[k], c = pv1 + h1[k];
            s += a + c; ss += a * a + c * c;
            mx0 = fmaxf(mx0, a); mn0 = fminf(mn0, a);
            mx1 = fmaxf(mx1, c); mn1 = fminf(mn1, c);
        }
        hmm[off0] = ((unsigned int)f2bf(mx0) << 16) | f2bf(mn0);
        hmm[off1] = ((unsigned int)f2bf(mx1) << 16) | f2bf(mn1);
    }
    atomicAdd(&stats[b * 512 + o], s);
    atomicAdd(&stats[b * 512 + NOUT + o], ss);
}

// ---------------- kernel 4: normalize + relu + max_k, transposed store; 512 thr ----------------
__global__ __launch_bounds__(512) void final_kernel(const unsigned int* __restrict__ hmm,
                                                    const float* __restrict__ stats,
                                                    const float* __restrict__ gamma,
                                                    const float* __restrict__ beta,
                                                    float* __restrict__ out) {
    __shared__ float tr[256 * 17];
    const int b = blockIdx.x, n0 = blockIdx.y * 16;
    const int tid = threadIdx.x;
    const int o = tid & 255, qh = tid >> 8;
    float sum = 0.f, sumsq = 0.f;
#pragma unroll
    for (int i = 0; i < 8; ++i) {
        sum   += stats[i * 512 + o];
        sumsq += stats[i * 512 + NOUT + o];
    }
    const float inv = 1.f / (float)TOTCNT;
    float mean = sum * inv;
    float var  = sumsq * inv - mean * mean;
    float g    = gamma[o] / sqrtf(var + 1e-5f);
    float bet  = beta[o];
    const bool pos = (g >= 0.f);
#pragma unroll
    for (int qq = 0; qq < 8; ++qq) {
        const int qi = qh * 8 + qq;
        size_t off = (size_t)(b * NPTS + n0 + qi) * NOUT + o;
        unsigned int w = hmm[off];
        float v = bf2f(pos ? (unsigned short)(w >> 16) : (unsigned short)(w & 0xFFFFu));
        float hn = (v - mean) * g + bet;
        tr[o * 17 + qi] = fmaxf(hn, 0.f);
    }
    __syncthreads();
    int oo = tid >> 4, qq = tid & 15;    // oo 0..31
    for (int pass = 0; pass < 8; ++pass) {
        int o_ = pass * 32 + oo;
        out[((size_t)b * NOUT + o_) * NPTS + n0 + qq] = tr[o_ * 17 + qq];
    }
}

extern "C" void kernel_launch(void* const* d_in, const int* in_sizes, int n_in,
                              void* d_out, int out_size, void* d_ws, size_t ws_size,
                              hipStream_t stream) {
    (void)in_sizes; (void)n_in; (void)out_size; (void)ws_size;
    const float* x     = (const float*)d_in[0];
    const float* W     = (const float*)d_in[1];
    const float* gamma = (const float*)d_in[2];
    const float* beta  = (const float*)d_in[3];
    float* out = (float*)d_out;

    char* ws = (char*)d_ws;
    float*          p     = (float*)ws;                                   // 16 MB fp32
    unsigned short* q     = (unsigned short*)(ws + (16u << 20));          // 8 MB bf16
    unsigned short* xhi   = (unsigned short*)(ws + (24u << 20));          // 4 MB
    unsigned short* xlo   = (unsigned short*)(ws + (28u << 20));          // 4 MB
    unsigned int*   hmm   = (unsigned int*)(ws + (32u << 20));            // 16 MB
    unsigned short* whi   = (unsigned short*)(ws + (48u << 20));          // 128 KB
    unsigned short* wlo   = (unsigned short*)(ws + (48u << 20) + 131072); // 128 KB
    float*          pd    = (float*)(ws + (49u << 20));                   // 2.25 MB
    int*            pi    = (int*)  (ws + (52u << 20));                   // 2.25 MB
    float*          sqh   = (float*)(ws + (55u << 20));                   // 64 KB
    float*          stats = (float*)(ws + (55u << 20) + 65536);           // 16 KB

    prep_kernel  <<<dim3(8, 33),    256, 0, stream>>>(x, W, xhi, xlo, whi, wlo, sqh, stats);
    knnpq_mfma   <<<dim3(8, 32, 8), 256, 0, stream>>>(xhi, xlo, sqh, whi, wlo, pd, pi, p, q);
    stats2_kernel<<<dim3(8, 128),   512, 0, stream>>>(p, q, pd, pi, stats, hmm);
    final_kernel <<<dim3(8, 128),   512, 0, stream>>>(hmm, stats, gamma, beta, out);
}